// Round 1
// baseline (12.237 us; speedup 1.0000x reference)
//
#include <hip/hip_runtime.h>

// Problem constants (fixed by the reference's setup_inputs)
#define BB 8
#define NN 16
#define KK 128
#define HH 64
#define WW 64
#define HWPX (HH * WW)

// Kernel 1: one block per (b, n) heatmap. Compact positive pixel coords into
// LDS, then threads 0..K-1 each own one keypoint: min squared distance over
// the positive list, classify pos/neg, block-reduce 3 partials.
__global__ __launch_bounds__(256) void kp_loss_partials(
    const float* __restrict__ all_scores,   // [B, K, N]
    const float* __restrict__ gt_heatmap,   // [B, N, H, W]
    const float* __restrict__ keypoints,    // [B, K, 2] (row, col)
    float* __restrict__ partials)           // [B*N, 3]
{
    __shared__ float sh_r[HWPX];   // positive pixel rows
    __shared__ float sh_c[HWPX];   // positive pixel cols
    __shared__ int   sh_count;
    __shared__ float red0[256], red1[256], red2[256];

    const int blk = blockIdx.x;            // b * N + n
    const int b   = blk / NN;
    const int n   = blk % NN;
    const int tid = threadIdx.x;

    if (tid == 0) sh_count = 0;
    __syncthreads();

    // Compact positives. Order is irrelevant (we only take a min).
    const float* hm = gt_heatmap + (size_t)blk * HWPX;
    for (int i = tid; i < HWPX; i += 256) {
        if (hm[i] > 0.0f) {
            int slot = atomicAdd(&sh_count, 1);
            sh_r[slot] = (float)(i >> 6);        // row = i / W
            sh_c[slot] = (float)(i & (WW - 1));  // col = i % W
        }
    }
    __syncthreads();
    const int cnt = sh_count;   // >= 1 by construction (pixel (0,0) forced positive)

    float pos_c = 0.0f, neg_c = 0.0f, ncnt = 0.0f;
    if (tid < KK) {
        const int k = tid;
        const float kr = keypoints[((size_t)b * KK + k) * 2 + 0];
        const float kc = keypoints[((size_t)b * KK + k) * 2 + 1];
        float dmin2 = INFINITY;
        for (int m = 0; m < cnt; ++m) {
            const float dr = kr - sh_r[m];
            const float dc = kc - sh_c[m];
            dmin2 = fminf(dmin2, dr * dr + dc * dc);
        }
        const float score = all_scores[((size_t)b * KK + k) * NN + n];
        if (dmin2 < 1.0f) {
            const float dmin = sqrtf(dmin2);
            pos_c = 10000.0f / (1.0f + __expf(dmin)) * __logf(score);
        } else {
            neg_c = __logf(1.0f - score);
            ncnt  = 1.0f;
        }
    }

    red0[tid] = pos_c; red1[tid] = neg_c; red2[tid] = ncnt;
    __syncthreads();
    for (int s = 128; s > 0; s >>= 1) {
        if (tid < s) {
            red0[tid] += red0[tid + s];
            red1[tid] += red1[tid + s];
            red2[tid] += red2[tid + s];
        }
        __syncthreads();
    }
    if (tid == 0) {
        partials[blk * 3 + 0] = red0[0];
        partials[blk * 3 + 1] = red1[0];
        partials[blk * 3 + 2] = red2[0];
    }
}

// Kernel 2: fold 128 partial triples into the scalar loss.
__global__ __launch_bounds__(128) void kp_loss_finalize(
    const float* __restrict__ partials, float* __restrict__ out)
{
    __shared__ float red0[128], red1[128], red2[128];
    const int tid = threadIdx.x;
    red0[tid] = partials[tid * 3 + 0];
    red1[tid] = partials[tid * 3 + 1];
    red2[tid] = partials[tid * 3 + 2];
    __syncthreads();
    for (int s = 64; s > 0; s >>= 1) {
        if (tid < s) {
            red0[tid] += red0[tid + s];
            red1[tid] += red1[tid + s];
            red2[tid] += red2[tid + s];
        }
        __syncthreads();
    }
    if (tid == 0) {
        const float pos_sum = red0[0];
        const float neg_sum = red1[0];
        const float cnt     = red2[0];
        float loss = -pos_sum;
        if (cnt > 0.0f) loss -= (10000.0f / cnt) * neg_sum;
        out[0] = loss;
    }
}

extern "C" void kernel_launch(void* const* d_in, const int* in_sizes, int n_in,
                              void* d_out, int out_size, void* d_ws, size_t ws_size,
                              hipStream_t stream) {
    const float* all_scores = (const float*)d_in[0];  // [B, K, N]
    const float* gt_heatmap = (const float*)d_in[1];  // [B, N, H, W]
    const float* keypoints  = (const float*)d_in[2];  // [B, K, 2]
    float* out = (float*)d_out;
    float* partials = (float*)d_ws;                   // 128 * 3 floats

    kp_loss_partials<<<BB * NN, 256, 0, stream>>>(all_scores, gt_heatmap, keypoints, partials);
    kp_loss_finalize<<<1, 128, 0, stream>>>(partials, out);
}